// Round 1
// baseline (2771.778 us; speedup 1.0000x reference)
//
#include <hip/hip_runtime.h>
#include <hip/hip_bf16.h>
#include <math.h>

#define N_NUC_C 100000
#define N_NN_C  1600000
#define EMB_C   128
#define MSG_C   32
#define OUT_C   128

__device__ __forceinline__ float silu_f(float y) {
    return y / (1.0f + __expf(-y));
}

// ---------------------------------------------------------------------------
// Kernel A: node projections  proj[pr][n][c] = embed[n] @ W + b
// grid = (ceil(N/256), 4): blockIdx.y selects {s,r} x {col half} so the
// weight pointer is wave-uniform -> W loads become s_loads (scalar operand
// FMAs, 1 instr/MAC).
// ---------------------------------------------------------------------------
__global__ __launch_bounds__(256) void proj_kernel(
    const float* __restrict__ s_embed, const float* __restrict__ r_embed,
    const float* __restrict__ W_s, const float* __restrict__ b_s,
    const float* __restrict__ W_r, const float* __restrict__ b_r,
    float* __restrict__ proj /* [2][N_NUC][MSG] */)
{
    const int n   = blockIdx.x * blockDim.x + threadIdx.x;
    const int sub = blockIdx.y;       // 0..3
    const int pr  = sub >> 1;         // 0 = sender proj, 1 = receiver proj
    const int c0  = (sub & 1) * 16;   // column half
    if (n >= N_NUC_C) return;

    const float* __restrict__ src = pr ? r_embed : s_embed;
    const float* __restrict__ W   = pr ? W_r : W_s;
    const float* __restrict__ b   = pr ? b_r : b_s;
    float* __restrict__ dst = proj + (size_t)pr * N_NUC_C * MSG_C;

    float acc[16];
    #pragma unroll
    for (int i = 0; i < 16; ++i) acc[i] = b[c0 + i];

    const float* row = src + (size_t)n * EMB_C;
    #pragma unroll 4
    for (int k = 0; k < EMB_C; k += 4) {
        const float4 rv = *reinterpret_cast<const float4*>(row + k);
        #pragma unroll
        for (int i = 0; i < 16; ++i) {
            acc[i] = fmaf(rv.x, W[(k + 0) * MSG_C + c0 + i], acc[i]);
            acc[i] = fmaf(rv.y, W[(k + 1) * MSG_C + c0 + i], acc[i]);
            acc[i] = fmaf(rv.z, W[(k + 2) * MSG_C + c0 + i], acc[i]);
            acc[i] = fmaf(rv.w, W[(k + 3) * MSG_C + c0 + i], acc[i]);
        }
    }

    float4* d = reinterpret_cast<float4*>(dst + (size_t)n * MSG_C + c0);
    d[0] = make_float4(acc[0],  acc[1],  acc[2],  acc[3]);
    d[1] = make_float4(acc[4],  acc[5],  acc[6],  acc[7]);
    d[2] = make_float4(acc[8],  acc[9],  acc[10], acc[11]);
    d[3] = make_float4(acc[12], acc[13], acc[14], acc[15]);
}

// ---------------------------------------------------------------------------
// Kernel B: per-edge gather + LayerNorm + SiLU + gate (e @ W_e) + scatter-add.
// Thread-per-edge; all 32 channels in registers. W_e / ln_scale / ln_bias are
// wave-uniform -> scalar loads. Fully unrolled so ev[] stays in registers.
// ---------------------------------------------------------------------------
__global__ __launch_bounds__(256) void edge_kernel(
    const float* __restrict__ proj,      // [2][N_NUC][MSG]
    const float* __restrict__ e_embed,   // [N_NN][MSG]
    const int*   __restrict__ senders,
    const int*   __restrict__ receivers,
    const float* __restrict__ ln_scale,
    const float* __restrict__ ln_bias,
    const float* __restrict__ W_e,       // [MSG][MSG]
    float*       __restrict__ msg)       // [N_NUC][MSG], pre-zeroed
{
    const int e = blockIdx.x * blockDim.x + threadIdx.x;
    if (e >= N_NN_C) return;
    const int s = senders[e];
    const int r = receivers[e];

    const float4* ps = reinterpret_cast<const float4*>(proj + (size_t)s * MSG_C);
    const float4* pq = reinterpret_cast<const float4*>(proj + (size_t)(N_NUC_C + r) * MSG_C);

    float x[MSG_C];
    #pragma unroll
    for (int q = 0; q < 8; ++q) {
        const float4 a = ps[q];
        const float4 b = pq[q];
        x[4*q+0] = a.x + b.x;
        x[4*q+1] = a.y + b.y;
        x[4*q+2] = a.z + b.z;
        x[4*q+3] = a.w + b.w;
    }

    // LayerNorm over the 32 channels (all in registers)
    float mu = 0.0f;
    #pragma unroll
    for (int c = 0; c < MSG_C; ++c) mu += x[c];
    mu *= (1.0f / MSG_C);
    float var = 0.0f;
    #pragma unroll
    for (int c = 0; c < MSG_C; ++c) { const float d = x[c] - mu; var = fmaf(d, d, var); }
    var *= (1.0f / MSG_C);
    const float rs = rsqrtf(var + 1e-6f);

    #pragma unroll
    for (int c = 0; c < MSG_C; ++c) {
        const float y = (x[c] - mu) * rs * ln_scale[c] + ln_bias[c];
        x[c] = silu_f(y);
    }

    // gate = e_embed[e] @ W_e   (1024 scalar-operand FMAs)
    float ev[MSG_C];
    const float4* ee = reinterpret_cast<const float4*>(e_embed + (size_t)e * MSG_C);
    #pragma unroll
    for (int q = 0; q < 8; ++q) {
        const float4 v = ee[q];
        ev[4*q+0] = v.x; ev[4*q+1] = v.y; ev[4*q+2] = v.z; ev[4*q+3] = v.w;
    }
    float g[MSG_C];
    #pragma unroll
    for (int c = 0; c < MSG_C; ++c) g[c] = 0.0f;
    #pragma unroll
    for (int k = 0; k < MSG_C; ++k) {
        const float ek = ev[k];
        #pragma unroll
        for (int c = 0; c < MSG_C; ++c)
            g[c] = fmaf(ek, W_e[k * MSG_C + c], g[c]);
    }

    float* mrow = msg + (size_t)r * MSG_C;
    #pragma unroll
    for (int c = 0; c < MSG_C; ++c)
        atomicAdd(mrow + c, x[c] * g[c]);
}

// ---------------------------------------------------------------------------
// Kernel C: out[n][j] = silu( (msg[n] . W_out[:,j]) * norm[n] )
// Grid-stride over nodes; each thread owns column j with W_out[:,j] in regs.
// ---------------------------------------------------------------------------
__global__ __launch_bounds__(256) void out_kernel(
    const float* __restrict__ msg,    // [N_NUC][MSG]
    const float* __restrict__ norm,   // [N_NUC]
    const float* __restrict__ W_out,  // [MSG][OUT]
    float*       __restrict__ out)    // [N_NUC][OUT]
{
    const int j     = threadIdx.x & (OUT_C - 1);   // 0..127
    const int local = threadIdx.x >> 7;            // 0..1

    float w[MSG_C];
    #pragma unroll
    for (int k = 0; k < MSG_C; ++k) w[k] = W_out[k * OUT_C + j];

    for (int n = blockIdx.x * 2 + local; n < N_NUC_C; n += gridDim.x * 2) {
        const float4* m4 = reinterpret_cast<const float4*>(msg + (size_t)n * MSG_C);
        float acc = 0.0f;
        #pragma unroll
        for (int q = 0; q < 8; ++q) {
            const float4 mv = m4[q];
            acc = fmaf(mv.x, w[4*q+0], acc);
            acc = fmaf(mv.y, w[4*q+1], acc);
            acc = fmaf(mv.z, w[4*q+2], acc);
            acc = fmaf(mv.w, w[4*q+3], acc);
        }
        acc *= norm[n];
        out[(size_t)n * OUT_C + j] = silu_f(acc);
    }
}

extern "C" void kernel_launch(void* const* d_in, const int* in_sizes, int n_in,
                              void* d_out, int out_size, void* d_ws, size_t ws_size,
                              hipStream_t stream) {
    const float* s_embed   = (const float*)d_in[0];
    const float* r_embed   = (const float*)d_in[1];
    const float* e_embed   = (const float*)d_in[2];
    const float* norm      = (const float*)d_in[3];
    const int*   senders   = (const int*)d_in[4];
    const int*   receivers = (const int*)d_in[5];
    const float* W_s       = (const float*)d_in[6];
    const float* b_s       = (const float*)d_in[7];
    const float* W_r       = (const float*)d_in[8];
    const float* b_r       = (const float*)d_in[9];
    const float* ln_scale  = (const float*)d_in[10];
    const float* ln_bias   = (const float*)d_in[11];
    const float* W_e       = (const float*)d_in[12];
    const float* W_out     = (const float*)d_in[13];
    float* out = (float*)d_out;

    float* proj = (float*)d_ws;                               // [2][N_NUC][MSG]
    float* msg  = proj + (size_t)2 * N_NUC_C * MSG_C;         // [N_NUC][MSG]

    // msg accumulator must be zeroed every call (ws is not re-poisoned).
    hipMemsetAsync(msg, 0, (size_t)N_NUC_C * MSG_C * sizeof(float), stream);

    dim3 pgrid((N_NUC_C + 255) / 256, 4);
    proj_kernel<<<pgrid, 256, 0, stream>>>(s_embed, r_embed, W_s, b_s, W_r, b_r, proj);

    edge_kernel<<<(N_NN_C + 255) / 256, 256, 0, stream>>>(
        proj, e_embed, senders, receivers, ln_scale, ln_bias, W_e, msg);

    out_kernel<<<2048, 256, 0, stream>>>(msg, norm, W_out, out);
}

// Round 2
// 1040.162 us; speedup vs baseline: 2.6648x; 2.6648x over previous
//
#include <hip/hip_runtime.h>
#include <hip/hip_bf16.h>
#include <math.h>

#define N_NUC_C 100000
#define N_NN_C  1600000
#define EMB_C   128
#define MSG_C   32
#define OUT_C   128
#define NB1     98   // ceil(N_NUC / 1024) for the scan

__device__ __forceinline__ float silu_f(float y) {
    return y / (1.0f + __expf(-y));
}

// ---------------------------------------------------------------------------
// Kernel A: node projections  proj[pr][n][c] = embed[n] @ W + b
// blockIdx.y selects {s,r} x {col half} -> weight pointer wave-uniform ->
// W loads are s_loads (scalar-operand FMAs).
// ---------------------------------------------------------------------------
__global__ __launch_bounds__(256) void proj_kernel(
    const float* __restrict__ s_embed, const float* __restrict__ r_embed,
    const float* __restrict__ W_s, const float* __restrict__ b_s,
    const float* __restrict__ W_r, const float* __restrict__ b_r,
    float* __restrict__ proj /* [2][N_NUC][MSG] */)
{
    const int n   = blockIdx.x * blockDim.x + threadIdx.x;
    const int sub = blockIdx.y;       // 0..3
    const int pr  = sub >> 1;
    const int c0  = (sub & 1) * 16;
    if (n >= N_NUC_C) return;

    const float* __restrict__ src = pr ? r_embed : s_embed;
    const float* __restrict__ W   = pr ? W_r : W_s;
    const float* __restrict__ b   = pr ? b_r : b_s;
    float* __restrict__ dst = proj + (size_t)pr * N_NUC_C * MSG_C;

    float acc[16];
    #pragma unroll
    for (int i = 0; i < 16; ++i) acc[i] = b[c0 + i];

    const float* row = src + (size_t)n * EMB_C;
    #pragma unroll 4
    for (int k = 0; k < EMB_C; k += 4) {
        const float4 rv = *reinterpret_cast<const float4*>(row + k);
        #pragma unroll
        for (int i = 0; i < 16; ++i) {
            acc[i] = fmaf(rv.x, W[(k + 0) * MSG_C + c0 + i], acc[i]);
            acc[i] = fmaf(rv.y, W[(k + 1) * MSG_C + c0 + i], acc[i]);
            acc[i] = fmaf(rv.z, W[(k + 2) * MSG_C + c0 + i], acc[i]);
            acc[i] = fmaf(rv.w, W[(k + 3) * MSG_C + c0 + i], acc[i]);
        }
    }

    float4* d = reinterpret_cast<float4*>(dst + (size_t)n * MSG_C + c0);
    d[0] = make_float4(acc[0],  acc[1],  acc[2],  acc[3]);
    d[1] = make_float4(acc[4],  acc[5],  acc[6],  acc[7]);
    d[2] = make_float4(acc[8],  acc[9],  acc[10], acc[11]);
    d[3] = make_float4(acc[12], acc[13], acc[14], acc[15]);
}

// ---------------------------------------------------------------------------
// CSR build: rank pass (the only atomics left: 1.6M int adds)
// ---------------------------------------------------------------------------
__global__ __launch_bounds__(256) void rank_kernel(
    const int* __restrict__ receivers, int* __restrict__ cnt,
    int* __restrict__ rank)
{
    const int e = blockIdx.x * blockDim.x + threadIdx.x;
    if (e >= N_NN_C) return;
    rank[e] = atomicAdd(&cnt[receivers[e]], 1);
}

// Exclusive scan of cnt[N_NUC] -> offsets. Three tiny kernels.
__global__ __launch_bounds__(256) void scan1_kernel(
    const int* __restrict__ cnt, int* __restrict__ excl, int* __restrict__ blockTot)
{
    __shared__ int waveTot[4];
    const int t = threadIdx.x, b = blockIdx.x;
    const int lane = t & 63, wid = t >> 6;
    const int base = b * 1024 + t * 4;

    int d0 = (base + 0 < N_NUC_C) ? cnt[base + 0] : 0;
    int d1 = (base + 1 < N_NUC_C) ? cnt[base + 1] : 0;
    int d2 = (base + 2 < N_NUC_C) ? cnt[base + 2] : 0;
    int d3 = (base + 3 < N_NUC_C) ? cnt[base + 3] : 0;
    const int s = d0 + d1 + d2 + d3;

    int incl = s;
    #pragma unroll
    for (int off = 1; off < 64; off <<= 1) {
        int v = __shfl_up(incl, off);
        if (lane >= off) incl += v;
    }
    const int wexcl = incl - s;
    if (lane == 63) waveTot[wid] = incl;
    __syncthreads();
    int wbase = 0;
    for (int w = 0; w < wid; ++w) wbase += waveTot[w];
    const int e0 = wbase + wexcl;

    if (base + 0 < N_NUC_C) excl[base + 0] = e0;
    if (base + 1 < N_NUC_C) excl[base + 1] = e0 + d0;
    if (base + 2 < N_NUC_C) excl[base + 2] = e0 + d0 + d1;
    if (base + 3 < N_NUC_C) excl[base + 3] = e0 + d0 + d1 + d2;
    if (t == 255) blockTot[b] = wbase + incl;
}

__global__ __launch_bounds__(128) void scan2_kernel(
    const int* __restrict__ blockTot, int* __restrict__ blockOff)
{
    __shared__ int sh[128];
    const int t = threadIdx.x;
    const int v = (t < NB1) ? blockTot[t] : 0;
    sh[t] = v;
    __syncthreads();
    #pragma unroll
    for (int off = 1; off < 128; off <<= 1) {
        int x = 0;
        if (t >= off) x = sh[t - off];
        __syncthreads();
        sh[t] += x;
        __syncthreads();
    }
    if (t < NB1) blockOff[t] = sh[t] - v;
}

__global__ __launch_bounds__(256) void scan3_kernel(
    const int* __restrict__ excl, const int* __restrict__ blockOff,
    int* __restrict__ offsets)
{
    const int n = blockIdx.x * blockDim.x + threadIdx.x;
    if (n < N_NUC_C) offsets[n] = excl[n] + blockOff[n >> 10];
    if (n == 0) offsets[N_NUC_C] = N_NN_C;
}

__global__ __launch_bounds__(256) void scatter_kernel(
    const int* __restrict__ receivers, const int* __restrict__ rank,
    const int* __restrict__ offsets, int* __restrict__ edge_order)
{
    const int e = blockIdx.x * blockDim.x + threadIdx.x;
    if (e >= N_NN_C) return;
    edge_order[offsets[receivers[e]] + rank[e]] = e;
}

// ---------------------------------------------------------------------------
// Gather-compute: one thread per node. Per incoming edge: gather projections,
// LayerNorm + SiLU, gate = e_embed@W_e (W_e wave-uniform -> s_loads),
// accumulate in registers. One 128B store per node. Zero f32 atomics.
// ---------------------------------------------------------------------------
__global__ __launch_bounds__(256) void gather_kernel(
    const float* __restrict__ proj,      // [2][N_NUC][MSG]
    const float* __restrict__ e_embed,   // [N_NN][MSG]
    const int*   __restrict__ senders,
    const int*   __restrict__ edge_order,
    const int*   __restrict__ offsets,
    const float* __restrict__ ln_scale,
    const float* __restrict__ ln_bias,
    const float* __restrict__ W_e,       // [MSG][MSG]
    float*       __restrict__ msg)       // [N_NUC][MSG]
{
    const int n = blockIdx.x * blockDim.x + threadIdx.x;
    if (n >= N_NUC_C) return;
    const int beg = offsets[n];
    const int end = offsets[n + 1];

    float pr[MSG_C];
    {
        const float4* p = reinterpret_cast<const float4*>(proj + (size_t)(N_NUC_C + n) * MSG_C);
        #pragma unroll
        for (int q = 0; q < 8; ++q) {
            const float4 v = p[q];
            pr[4*q+0] = v.x; pr[4*q+1] = v.y; pr[4*q+2] = v.z; pr[4*q+3] = v.w;
        }
    }

    float acc[MSG_C];
    #pragma unroll
    for (int c = 0; c < MSG_C; ++c) acc[c] = 0.0f;

    // one-ahead prefetch of the index chain (edge_order -> senders)
    int e = 0, s = 0;
    if (beg < end) { e = edge_order[beg]; s = senders[e]; }

    for (int i = beg; i < end; ++i) {
        const int ec = e, sc = s;
        if (i + 1 < end) { e = edge_order[i + 1]; s = senders[e]; }

        // issue both row loads up front; gate compute hides the proj load
        float x[MSG_C], ev[MSG_C];
        {
            const float4* ps = reinterpret_cast<const float4*>(proj + (size_t)sc * MSG_C);
            const float4* ee = reinterpret_cast<const float4*>(e_embed + (size_t)ec * MSG_C);
            #pragma unroll
            for (int q = 0; q < 8; ++q) {
                const float4 a = ee[q];
                ev[4*q+0] = a.x; ev[4*q+1] = a.y; ev[4*q+2] = a.z; ev[4*q+3] = a.w;
            }
            #pragma unroll
            for (int q = 0; q < 8; ++q) {
                const float4 a = ps[q];
                x[4*q+0] = a.x; x[4*q+1] = a.y; x[4*q+2] = a.z; x[4*q+3] = a.w;
            }
        }

        // gate = e_embed[e] @ W_e  (wave-uniform W_e -> scalar operands)
        float g[MSG_C];
        #pragma unroll
        for (int c = 0; c < MSG_C; ++c) g[c] = 0.0f;
        #pragma unroll
        for (int k = 0; k < MSG_C; ++k) {
            const float ek = ev[k];
            #pragma unroll
            for (int c = 0; c < MSG_C; ++c)
                g[c] = fmaf(ek, W_e[k * MSG_C + c], g[c]);
        }

        // x = proj_s[sender] + proj_r[n], then LayerNorm + SiLU
        #pragma unroll
        for (int c = 0; c < MSG_C; ++c) x[c] += pr[c];

        float mu = 0.0f;
        #pragma unroll
        for (int c = 0; c < MSG_C; ++c) mu += x[c];
        mu *= (1.0f / MSG_C);
        float var = 0.0f;
        #pragma unroll
        for (int c = 0; c < MSG_C; ++c) { const float d = x[c] - mu; var = fmaf(d, d, var); }
        var *= (1.0f / MSG_C);
        const float rs = rsqrtf(var + 1e-6f);

        #pragma unroll
        for (int c = 0; c < MSG_C; ++c) {
            const float y = (x[c] - mu) * rs * ln_scale[c] + ln_bias[c];
            acc[c] = fmaf(silu_f(y), g[c], acc[c]);
        }
    }

    float4* d = reinterpret_cast<float4*>(msg + (size_t)n * MSG_C);
    #pragma unroll
    for (int q = 0; q < 8; ++q)
        d[q] = make_float4(acc[4*q+0], acc[4*q+1], acc[4*q+2], acc[4*q+3]);
}

// ---------------------------------------------------------------------------
// Fallback edge kernel (R1 path, used only if ws_size is too small)
// ---------------------------------------------------------------------------
__global__ __launch_bounds__(256) void edge_kernel(
    const float* __restrict__ proj, const float* __restrict__ e_embed,
    const int* __restrict__ senders, const int* __restrict__ receivers,
    const float* __restrict__ ln_scale, const float* __restrict__ ln_bias,
    const float* __restrict__ W_e, float* __restrict__ msg)
{
    const int e = blockIdx.x * blockDim.x + threadIdx.x;
    if (e >= N_NN_C) return;
    const int s = senders[e];
    const int r = receivers[e];

    const float4* ps = reinterpret_cast<const float4*>(proj + (size_t)s * MSG_C);
    const float4* pq = reinterpret_cast<const float4*>(proj + (size_t)(N_NUC_C + r) * MSG_C);

    float x[MSG_C];
    #pragma unroll
    for (int q = 0; q < 8; ++q) {
        const float4 a = ps[q];
        const float4 b = pq[q];
        x[4*q+0] = a.x + b.x; x[4*q+1] = a.y + b.y;
        x[4*q+2] = a.z + b.z; x[4*q+3] = a.w + b.w;
    }
    float mu = 0.0f;
    #pragma unroll
    for (int c = 0; c < MSG_C; ++c) mu += x[c];
    mu *= (1.0f / MSG_C);
    float var = 0.0f;
    #pragma unroll
    for (int c = 0; c < MSG_C; ++c) { const float d = x[c] - mu; var = fmaf(d, d, var); }
    var *= (1.0f / MSG_C);
    const float rs = rsqrtf(var + 1e-6f);
    #pragma unroll
    for (int c = 0; c < MSG_C; ++c) {
        const float y = (x[c] - mu) * rs * ln_scale[c] + ln_bias[c];
        x[c] = silu_f(y);
    }
    float ev[MSG_C];
    const float4* ee = reinterpret_cast<const float4*>(e_embed + (size_t)e * MSG_C);
    #pragma unroll
    for (int q = 0; q < 8; ++q) {
        const float4 v = ee[q];
        ev[4*q+0] = v.x; ev[4*q+1] = v.y; ev[4*q+2] = v.z; ev[4*q+3] = v.w;
    }
    float g[MSG_C];
    #pragma unroll
    for (int c = 0; c < MSG_C; ++c) g[c] = 0.0f;
    #pragma unroll
    for (int k = 0; k < MSG_C; ++k) {
        const float ek = ev[k];
        #pragma unroll
        for (int c = 0; c < MSG_C; ++c) g[c] = fmaf(ek, W_e[k * MSG_C + c], g[c]);
    }
    float* mrow = msg + (size_t)r * MSG_C;
    #pragma unroll
    for (int c = 0; c < MSG_C; ++c) atomicAdd(mrow + c, x[c] * g[c]);
}

// ---------------------------------------------------------------------------
// Kernel C: out[n][j] = silu( (msg[n] . W_out[:,j]) * norm[n] )
// ---------------------------------------------------------------------------
__global__ __launch_bounds__(256) void out_kernel(
    const float* __restrict__ msg, const float* __restrict__ norm,
    const float* __restrict__ W_out, float* __restrict__ out)
{
    const int j     = threadIdx.x & (OUT_C - 1);
    const int local = threadIdx.x >> 7;

    float w[MSG_C];
    #pragma unroll
    for (int k = 0; k < MSG_C; ++k) w[k] = W_out[k * OUT_C + j];

    for (int n = blockIdx.x * 2 + local; n < N_NUC_C; n += gridDim.x * 2) {
        const float4* m4 = reinterpret_cast<const float4*>(msg + (size_t)n * MSG_C);
        float acc = 0.0f;
        #pragma unroll
        for (int q = 0; q < 8; ++q) {
            const float4 mv = m4[q];
            acc = fmaf(mv.x, w[4*q+0], acc);
            acc = fmaf(mv.y, w[4*q+1], acc);
            acc = fmaf(mv.z, w[4*q+2], acc);
            acc = fmaf(mv.w, w[4*q+3], acc);
        }
        acc *= norm[n];
        out[(size_t)n * OUT_C + j] = silu_f(acc);
    }
}

extern "C" void kernel_launch(void* const* d_in, const int* in_sizes, int n_in,
                              void* d_out, int out_size, void* d_ws, size_t ws_size,
                              hipStream_t stream) {
    const float* s_embed   = (const float*)d_in[0];
    const float* r_embed   = (const float*)d_in[1];
    const float* e_embed   = (const float*)d_in[2];
    const float* norm      = (const float*)d_in[3];
    const int*   senders   = (const int*)d_in[4];
    const int*   receivers = (const int*)d_in[5];
    const float* W_s       = (const float*)d_in[6];
    const float* b_s       = (const float*)d_in[7];
    const float* W_r       = (const float*)d_in[8];
    const float* b_r       = (const float*)d_in[9];
    const float* ln_scale  = (const float*)d_in[10];
    const float* ln_bias   = (const float*)d_in[11];
    const float* W_e       = (const float*)d_in[12];
    const float* W_out     = (const float*)d_in[13];
    float* out = (float*)d_out;

    char* ws = (char*)d_ws;
    size_t off = 0;
    auto alloc = [&](size_t bytes) { char* p = ws + off; off += (bytes + 15) & ~(size_t)15; return p; };

    float* proj       = (float*)alloc((size_t)2 * N_NUC_C * MSG_C * 4); // 25.6 MB
    float* msg        = (float*)alloc((size_t)N_NUC_C * MSG_C * 4);     // 12.8 MB
    int*   cnt        = (int*)  alloc((size_t)N_NUC_C * 4);
    int*   excl       = (int*)  alloc((size_t)N_NUC_C * 4);
    int*   offsets    = (int*)  alloc((size_t)(N_NUC_C + 1) * 4);
    int*   blockTot   = (int*)  alloc(128 * 4);
    int*   blockOff   = (int*)  alloc(128 * 4);
    int*   rank       = (int*)  alloc((size_t)N_NN_C * 4);              // 6.4 MB
    int*   edge_order = (int*)  alloc((size_t)N_NN_C * 4);              // 6.4 MB

    dim3 pgrid((N_NUC_C + 255) / 256, 4);
    proj_kernel<<<pgrid, 256, 0, stream>>>(s_embed, r_embed, W_s, b_s, W_r, b_r, proj);

    if (off <= ws_size) {
        // --- CSR gather path (no f32 atomics) ---
        hipMemsetAsync(cnt, 0, (size_t)N_NUC_C * 4, stream);
        rank_kernel<<<(N_NN_C + 255) / 256, 256, 0, stream>>>(receivers, cnt, rank);
        scan1_kernel<<<NB1, 256, 0, stream>>>(cnt, excl, blockTot);
        scan2_kernel<<<1, 128, 0, stream>>>(blockTot, blockOff);
        scan3_kernel<<<(N_NUC_C + 255) / 256, 256, 0, stream>>>(excl, blockOff, offsets);
        scatter_kernel<<<(N_NN_C + 255) / 256, 256, 0, stream>>>(receivers, rank, offsets, edge_order);
        gather_kernel<<<(N_NUC_C + 255) / 256, 256, 0, stream>>>(
            proj, e_embed, senders, edge_order, offsets, ln_scale, ln_bias, W_e, msg);
    } else {
        // --- fallback: R1 atomic path ---
        hipMemsetAsync(msg, 0, (size_t)N_NUC_C * MSG_C * 4, stream);
        edge_kernel<<<(N_NN_C + 255) / 256, 256, 0, stream>>>(
            proj, e_embed, senders, receivers, ln_scale, ln_bias, W_e, msg);
    }

    out_kernel<<<2048, 256, 0, stream>>>(msg, norm, W_out, out);
}

// Round 3
// 477.324 us; speedup vs baseline: 5.8069x; 2.1792x over previous
//
#include <hip/hip_runtime.h>
#include <hip/hip_bf16.h>
#include <math.h>

#define N_NUC_C 100000
#define N_NN_C  1600000
#define EMB_C   128
#define MSG_C   32
#define OUT_C   128
#define NB1     98   // ceil(N_NUC / 1024) for the scan

__device__ __forceinline__ float silu_f(float y) {
    return y / (1.0f + __expf(-y));
}

// ---------------------------------------------------------------------------
// Kernel A: node projections  proj[pr][n][c] = embed[n] @ W + b
// ---------------------------------------------------------------------------
__global__ __launch_bounds__(256) void proj_kernel(
    const float* __restrict__ s_embed, const float* __restrict__ r_embed,
    const float* __restrict__ W_s, const float* __restrict__ b_s,
    const float* __restrict__ W_r, const float* __restrict__ b_r,
    float* __restrict__ proj /* [2][N_NUC][MSG] */)
{
    const int n   = blockIdx.x * blockDim.x + threadIdx.x;
    const int sub = blockIdx.y;       // 0..3
    const int pr  = sub >> 1;
    const int c0  = (sub & 1) * 16;
    if (n >= N_NUC_C) return;

    const float* __restrict__ src = pr ? r_embed : s_embed;
    const float* __restrict__ W   = pr ? W_r : W_s;
    const float* __restrict__ b   = pr ? b_r : b_s;
    float* __restrict__ dst = proj + (size_t)pr * N_NUC_C * MSG_C;

    float acc[16];
    #pragma unroll
    for (int i = 0; i < 16; ++i) acc[i] = b[c0 + i];

    const float* row = src + (size_t)n * EMB_C;
    #pragma unroll 4
    for (int k = 0; k < EMB_C; k += 4) {
        const float4 rv = *reinterpret_cast<const float4*>(row + k);
        #pragma unroll
        for (int i = 0; i < 16; ++i) {
            acc[i] = fmaf(rv.x, W[(k + 0) * MSG_C + c0 + i], acc[i]);
            acc[i] = fmaf(rv.y, W[(k + 1) * MSG_C + c0 + i], acc[i]);
            acc[i] = fmaf(rv.z, W[(k + 2) * MSG_C + c0 + i], acc[i]);
            acc[i] = fmaf(rv.w, W[(k + 3) * MSG_C + c0 + i], acc[i]);
        }
    }

    float4* d = reinterpret_cast<float4*>(dst + (size_t)n * MSG_C + c0);
    d[0] = make_float4(acc[0],  acc[1],  acc[2],  acc[3]);
    d[1] = make_float4(acc[4],  acc[5],  acc[6],  acc[7]);
    d[2] = make_float4(acc[8],  acc[9],  acc[10], acc[11]);
    d[3] = make_float4(acc[12], acc[13], acc[14], acc[15]);
}

// ---------------------------------------------------------------------------
// CSR build: rank pass (1.6M int atomics)
// ---------------------------------------------------------------------------
__global__ __launch_bounds__(256) void rank_kernel(
    const int* __restrict__ receivers, int* __restrict__ cnt,
    int* __restrict__ rank)
{
    const int e = blockIdx.x * blockDim.x + threadIdx.x;
    if (e >= N_NN_C) return;
    rank[e] = atomicAdd(&cnt[receivers[e]], 1);
}

// Exclusive scan of cnt[N_NUC] -> offsets. Three tiny kernels.
__global__ __launch_bounds__(256) void scan1_kernel(
    const int* __restrict__ cnt, int* __restrict__ excl, int* __restrict__ blockTot)
{
    __shared__ int waveTot[4];
    const int t = threadIdx.x, b = blockIdx.x;
    const int lane = t & 63, wid = t >> 6;
    const int base = b * 1024 + t * 4;

    int d0 = (base + 0 < N_NUC_C) ? cnt[base + 0] : 0;
    int d1 = (base + 1 < N_NUC_C) ? cnt[base + 1] : 0;
    int d2 = (base + 2 < N_NUC_C) ? cnt[base + 2] : 0;
    int d3 = (base + 3 < N_NUC_C) ? cnt[base + 3] : 0;
    const int s = d0 + d1 + d2 + d3;

    int incl = s;
    #pragma unroll
    for (int off = 1; off < 64; off <<= 1) {
        int v = __shfl_up(incl, off);
        if (lane >= off) incl += v;
    }
    const int wexcl = incl - s;
    if (lane == 63) waveTot[wid] = incl;
    __syncthreads();
    int wbase = 0;
    for (int w = 0; w < wid; ++w) wbase += waveTot[w];
    const int e0 = wbase + wexcl;

    if (base + 0 < N_NUC_C) excl[base + 0] = e0;
    if (base + 1 < N_NUC_C) excl[base + 1] = e0 + d0;
    if (base + 2 < N_NUC_C) excl[base + 2] = e0 + d0 + d1;
    if (base + 3 < N_NUC_C) excl[base + 3] = e0 + d0 + d1 + d2;
    if (t == 255) blockTot[b] = wbase + incl;
}

__global__ __launch_bounds__(128) void scan2_kernel(
    const int* __restrict__ blockTot, int* __restrict__ blockOff)
{
    __shared__ int sh[128];
    const int t = threadIdx.x;
    const int v = (t < NB1) ? blockTot[t] : 0;
    sh[t] = v;
    __syncthreads();
    #pragma unroll
    for (int off = 1; off < 128; off <<= 1) {
        int x = 0;
        if (t >= off) x = sh[t - off];
        __syncthreads();
        sh[t] += x;
        __syncthreads();
    }
    if (t < NB1) blockOff[t] = sh[t] - v;
}

__global__ __launch_bounds__(256) void scan3_kernel(
    const int* __restrict__ excl, const int* __restrict__ blockOff,
    int* __restrict__ offsets)
{
    const int n = blockIdx.x * blockDim.x + threadIdx.x;
    if (n < N_NUC_C) offsets[n] = excl[n] + blockOff[n >> 10];
    if (n == 0) offsets[N_NUC_C] = N_NN_C;
}

// ---------------------------------------------------------------------------
// Phase 1: edge-parallel compute in ORIGINAL edge order.
// Coalesced senders/receivers/rank/e_embed reads; proj gathered (L3-resident);
// plain 128B store to the edge's CSR slot. No atomics, no serial chains.
// ---------------------------------------------------------------------------
__global__ __launch_bounds__(256) void edge_compute_kernel(
    const float* __restrict__ proj,      // [2][N_NUC][MSG]
    const float* __restrict__ e_embed,   // [N_NN][MSG]
    const int*   __restrict__ senders,
    const int*   __restrict__ receivers,
    const int*   __restrict__ rank,
    const int*   __restrict__ offsets,
    const float* __restrict__ ln_scale,
    const float* __restrict__ ln_bias,
    const float* __restrict__ W_e,       // [MSG][MSG]
    float*       __restrict__ val)       // [N_NN][MSG] in CSR order
{
    const int e = blockIdx.x * blockDim.x + threadIdx.x;
    if (e >= N_NN_C) return;
    const int s   = senders[e];
    const int r   = receivers[e];
    const int dst = offsets[r] + rank[e];

    const float4* ps = reinterpret_cast<const float4*>(proj + (size_t)s * MSG_C);
    const float4* pq = reinterpret_cast<const float4*>(proj + (size_t)(N_NUC_C + r) * MSG_C);
    const float4* ee = reinterpret_cast<const float4*>(e_embed + (size_t)e * MSG_C);

    // issue all loads up front
    float x[MSG_C], ev[MSG_C];
    #pragma unroll
    for (int q = 0; q < 8; ++q) {
        const float4 v = ee[q];
        ev[4*q+0] = v.x; ev[4*q+1] = v.y; ev[4*q+2] = v.z; ev[4*q+3] = v.w;
    }
    #pragma unroll
    for (int q = 0; q < 8; ++q) {
        const float4 a = ps[q];
        const float4 b = pq[q];
        x[4*q+0] = a.x + b.x; x[4*q+1] = a.y + b.y;
        x[4*q+2] = a.z + b.z; x[4*q+3] = a.w + b.w;
    }

    // gate = e_embed[e] @ W_e  (wave-uniform W_e -> scalar operands)
    float g[MSG_C];
    #pragma unroll
    for (int c = 0; c < MSG_C; ++c) g[c] = 0.0f;
    #pragma unroll
    for (int k = 0; k < MSG_C; ++k) {
        const float ek = ev[k];
        #pragma unroll
        for (int c = 0; c < MSG_C; ++c)
            g[c] = fmaf(ek, W_e[k * MSG_C + c], g[c]);
    }

    // LayerNorm + SiLU on x
    float mu = 0.0f;
    #pragma unroll
    for (int c = 0; c < MSG_C; ++c) mu += x[c];
    mu *= (1.0f / MSG_C);
    float var = 0.0f;
    #pragma unroll
    for (int c = 0; c < MSG_C; ++c) { const float d = x[c] - mu; var = fmaf(d, d, var); }
    var *= (1.0f / MSG_C);
    const float rs = rsqrtf(var + 1e-6f);

    float4* d4 = reinterpret_cast<float4*>(val + (size_t)dst * MSG_C);
    #pragma unroll
    for (int q = 0; q < 8; ++q) {
        float o[4];
        #pragma unroll
        for (int i = 0; i < 4; ++i) {
            const int c = 4*q + i;
            const float y = (x[c] - mu) * rs * ln_scale[c] + ln_bias[c];
            o[i] = silu_f(y) * g[c];
        }
        d4[q] = make_float4(o[0], o[1], o[2], o[3]);
    }
}

// ---------------------------------------------------------------------------
// Phase 2: segmented sum of val rows per node. 8 threads per node, each owns
// a 16B chunk of the 128B row; segment reads are contiguous.
// ---------------------------------------------------------------------------
__global__ __launch_bounds__(256) void reduce_kernel(
    const float* __restrict__ val,      // [N_NN][MSG] CSR order
    const int*   __restrict__ offsets,
    float*       __restrict__ msg)      // [N_NUC][MSG]
{
    const int gid  = blockIdx.x * blockDim.x + threadIdx.x;
    const int n    = gid >> 3;
    const int part = gid & 7;
    if (n >= N_NUC_C) return;
    const int beg = offsets[n];
    const int end = offsets[n + 1];

    float4 acc = make_float4(0.f, 0.f, 0.f, 0.f);
    for (int i = beg; i < end; ++i) {
        const float4 v = *reinterpret_cast<const float4*>(val + (size_t)i * MSG_C + part * 4);
        acc.x += v.x; acc.y += v.y; acc.z += v.z; acc.w += v.w;
    }
    *reinterpret_cast<float4*>(msg + (size_t)n * MSG_C + part * 4) = acc;
}

// ---------------------------------------------------------------------------
// Fallback kernels (smaller ws_size): R2 gather path / R1 atomic path
// ---------------------------------------------------------------------------
__global__ __launch_bounds__(256) void scatter_kernel(
    const int* __restrict__ receivers, const int* __restrict__ rank,
    const int* __restrict__ offsets, int* __restrict__ edge_order)
{
    const int e = blockIdx.x * blockDim.x + threadIdx.x;
    if (e >= N_NN_C) return;
    edge_order[offsets[receivers[e]] + rank[e]] = e;
}

__global__ __launch_bounds__(256) void gather_kernel(
    const float* __restrict__ proj, const float* __restrict__ e_embed,
    const int* __restrict__ senders, const int* __restrict__ edge_order,
    const int* __restrict__ offsets, const float* __restrict__ ln_scale,
    const float* __restrict__ ln_bias, const float* __restrict__ W_e,
    float* __restrict__ msg)
{
    const int n = blockIdx.x * blockDim.x + threadIdx.x;
    if (n >= N_NUC_C) return;
    const int beg = offsets[n];
    const int end = offsets[n + 1];

    float pr[MSG_C];
    {
        const float4* p = reinterpret_cast<const float4*>(proj + (size_t)(N_NUC_C + n) * MSG_C);
        #pragma unroll
        for (int q = 0; q < 8; ++q) {
            const float4 v = p[q];
            pr[4*q+0] = v.x; pr[4*q+1] = v.y; pr[4*q+2] = v.z; pr[4*q+3] = v.w;
        }
    }
    float acc[MSG_C];
    #pragma unroll
    for (int c = 0; c < MSG_C; ++c) acc[c] = 0.0f;

    int e = 0, s = 0;
    if (beg < end) { e = edge_order[beg]; s = senders[e]; }

    for (int i = beg; i < end; ++i) {
        const int ec = e, sc = s;
        if (i + 1 < end) { e = edge_order[i + 1]; s = senders[e]; }

        float x[MSG_C], ev[MSG_C];
        const float4* ps = reinterpret_cast<const float4*>(proj + (size_t)sc * MSG_C);
        const float4* ee = reinterpret_cast<const float4*>(e_embed + (size_t)ec * MSG_C);
        #pragma unroll
        for (int q = 0; q < 8; ++q) {
            const float4 a = ee[q];
            ev[4*q+0] = a.x; ev[4*q+1] = a.y; ev[4*q+2] = a.z; ev[4*q+3] = a.w;
        }
        #pragma unroll
        for (int q = 0; q < 8; ++q) {
            const float4 a = ps[q];
            x[4*q+0] = a.x; x[4*q+1] = a.y; x[4*q+2] = a.z; x[4*q+3] = a.w;
        }
        float g[MSG_C];
        #pragma unroll
        for (int c = 0; c < MSG_C; ++c) g[c] = 0.0f;
        #pragma unroll
        for (int k = 0; k < MSG_C; ++k) {
            const float ek = ev[k];
            #pragma unroll
            for (int c = 0; c < MSG_C; ++c) g[c] = fmaf(ek, W_e[k * MSG_C + c], g[c]);
        }
        #pragma unroll
        for (int c = 0; c < MSG_C; ++c) x[c] += pr[c];
        float mu = 0.0f;
        #pragma unroll
        for (int c = 0; c < MSG_C; ++c) mu += x[c];
        mu *= (1.0f / MSG_C);
        float var = 0.0f;
        #pragma unroll
        for (int c = 0; c < MSG_C; ++c) { const float d = x[c] - mu; var = fmaf(d, d, var); }
        var *= (1.0f / MSG_C);
        const float rs = rsqrtf(var + 1e-6f);
        #pragma unroll
        for (int c = 0; c < MSG_C; ++c) {
            const float y = (x[c] - mu) * rs * ln_scale[c] + ln_bias[c];
            acc[c] = fmaf(silu_f(y), g[c], acc[c]);
        }
    }
    float4* d = reinterpret_cast<float4*>(msg + (size_t)n * MSG_C);
    #pragma unroll
    for (int q = 0; q < 8; ++q)
        d[q] = make_float4(acc[4*q+0], acc[4*q+1], acc[4*q+2], acc[4*q+3]);
}

__global__ __launch_bounds__(256) void edge_kernel(
    const float* __restrict__ proj, const float* __restrict__ e_embed,
    const int* __restrict__ senders, const int* __restrict__ receivers,
    const float* __restrict__ ln_scale, const float* __restrict__ ln_bias,
    const float* __restrict__ W_e, float* __restrict__ msg)
{
    const int e = blockIdx.x * blockDim.x + threadIdx.x;
    if (e >= N_NN_C) return;
    const int s = senders[e];
    const int r = receivers[e];
    const float4* ps = reinterpret_cast<const float4*>(proj + (size_t)s * MSG_C);
    const float4* pq = reinterpret_cast<const float4*>(proj + (size_t)(N_NUC_C + r) * MSG_C);
    float x[MSG_C];
    #pragma unroll
    for (int q = 0; q < 8; ++q) {
        const float4 a = ps[q];
        const float4 b = pq[q];
        x[4*q+0] = a.x + b.x; x[4*q+1] = a.y + b.y;
        x[4*q+2] = a.z + b.z; x[4*q+3] = a.w + b.w;
    }
    float mu = 0.0f;
    #pragma unroll
    for (int c = 0; c < MSG_C; ++c) mu += x[c];
    mu *= (1.0f / MSG_C);
    float var = 0.0f;
    #pragma unroll
    for (int c = 0; c < MSG_C; ++c) { const float d = x[c] - mu; var = fmaf(d, d, var); }
    var *= (1.0f / MSG_C);
    const float rs = rsqrtf(var + 1e-6f);
    #pragma unroll
    for (int c = 0; c < MSG_C; ++c) {
        const float y = (x[c] - mu) * rs * ln_scale[c] + ln_bias[c];
        x[c] = silu_f(y);
    }
    float ev[MSG_C];
    const float4* ee = reinterpret_cast<const float4*>(e_embed + (size_t)e * MSG_C);
    #pragma unroll
    for (int q = 0; q < 8; ++q) {
        const float4 v = ee[q];
        ev[4*q+0] = v.x; ev[4*q+1] = v.y; ev[4*q+2] = v.z; ev[4*q+3] = v.w;
    }
    float g[MSG_C];
    #pragma unroll
    for (int c = 0; c < MSG_C; ++c) g[c] = 0.0f;
    #pragma unroll
    for (int k = 0; k < MSG_C; ++k) {
        const float ek = ev[k];
        #pragma unroll
        for (int c = 0; c < MSG_C; ++c) g[c] = fmaf(ek, W_e[k * MSG_C + c], g[c]);
    }
    float* mrow = msg + (size_t)r * MSG_C;
    #pragma unroll
    for (int c = 0; c < MSG_C; ++c) atomicAdd(mrow + c, x[c] * g[c]);
}

// ---------------------------------------------------------------------------
// Kernel C: out[n][j] = silu( (msg[n] . W_out[:,j]) * norm[n] )
// ---------------------------------------------------------------------------
__global__ __launch_bounds__(256) void out_kernel(
    const float* __restrict__ msg, const float* __restrict__ norm,
    const float* __restrict__ W_out, float* __restrict__ out)
{
    const int j     = threadIdx.x & (OUT_C - 1);
    const int local = threadIdx.x >> 7;

    float w[MSG_C];
    #pragma unroll
    for (int k = 0; k < MSG_C; ++k) w[k] = W_out[k * OUT_C + j];

    for (int n = blockIdx.x * 2 + local; n < N_NUC_C; n += gridDim.x * 2) {
        const float4* m4 = reinterpret_cast<const float4*>(msg + (size_t)n * MSG_C);
        float acc = 0.0f;
        #pragma unroll
        for (int q = 0; q < 8; ++q) {
            const float4 mv = m4[q];
            acc = fmaf(mv.x, w[4*q+0], acc);
            acc = fmaf(mv.y, w[4*q+1], acc);
            acc = fmaf(mv.z, w[4*q+2], acc);
            acc = fmaf(mv.w, w[4*q+3], acc);
        }
        acc *= norm[n];
        out[(size_t)n * OUT_C + j] = silu_f(acc);
    }
}

extern "C" void kernel_launch(void* const* d_in, const int* in_sizes, int n_in,
                              void* d_out, int out_size, void* d_ws, size_t ws_size,
                              hipStream_t stream) {
    const float* s_embed   = (const float*)d_in[0];
    const float* r_embed   = (const float*)d_in[1];
    const float* e_embed   = (const float*)d_in[2];
    const float* norm      = (const float*)d_in[3];
    const int*   senders   = (const int*)d_in[4];
    const int*   receivers = (const int*)d_in[5];
    const float* W_s       = (const float*)d_in[6];
    const float* b_s       = (const float*)d_in[7];
    const float* W_r       = (const float*)d_in[8];
    const float* b_r       = (const float*)d_in[9];
    const float* ln_scale  = (const float*)d_in[10];
    const float* ln_bias   = (const float*)d_in[11];
    const float* W_e       = (const float*)d_in[12];
    const float* W_out     = (const float*)d_in[13];
    float* out = (float*)d_out;

    char* ws = (char*)d_ws;
    size_t off = 0;
    auto alloc = [&](size_t bytes) { char* p = ws + off; off += (bytes + 255) & ~(size_t)255; return p; };

    float* proj       = (float*)alloc((size_t)2 * N_NUC_C * MSG_C * 4); // 25.6 MB
    float* msg        = (float*)alloc((size_t)N_NUC_C * MSG_C * 4);     // 12.8 MB
    int*   cnt        = (int*)  alloc((size_t)N_NUC_C * 4);
    int*   excl       = (int*)  alloc((size_t)N_NUC_C * 4);
    int*   offsets    = (int*)  alloc((size_t)(N_NUC_C + 1) * 4);
    int*   blockTot   = (int*)  alloc(128 * 4);
    int*   blockOff   = (int*)  alloc(128 * 4);
    int*   rank       = (int*)  alloc((size_t)N_NN_C * 4);              // 6.4 MB
    int*   edge_order = (int*)  alloc((size_t)N_NN_C * 4);              // 6.4 MB
    const size_t off_mid = off;                                         // ~52.8 MB
    float* val        = (float*)alloc((size_t)N_NN_C * MSG_C * 4);      // 204.8 MB
    const size_t off_full = off;

    dim3 pgrid((N_NUC_C + 255) / 256, 4);
    proj_kernel<<<pgrid, 256, 0, stream>>>(s_embed, r_embed, W_s, b_s, W_r, b_r, proj);

    if (off_full <= ws_size) {
        // --- CSR + edge-parallel val + segmented reduce (no f32 atomics) ---
        hipMemsetAsync(cnt, 0, (size_t)N_NUC_C * 4, stream);
        rank_kernel<<<(N_NN_C + 255) / 256, 256, 0, stream>>>(receivers, cnt, rank);
        scan1_kernel<<<NB1, 256, 0, stream>>>(cnt, excl, blockTot);
        scan2_kernel<<<1, 128, 0, stream>>>(blockTot, blockOff);
        scan3_kernel<<<(N_NUC_C + 255) / 256, 256, 0, stream>>>(excl, blockOff, offsets);
        edge_compute_kernel<<<(N_NN_C + 255) / 256, 256, 0, stream>>>(
            proj, e_embed, senders, receivers, rank, offsets, ln_scale, ln_bias, W_e, val);
        reduce_kernel<<<(N_NUC_C * 8 + 255) / 256, 256, 0, stream>>>(val, offsets, msg);
    } else if (off_mid <= ws_size) {
        // --- R2 gather path ---
        hipMemsetAsync(cnt, 0, (size_t)N_NUC_C * 4, stream);
        rank_kernel<<<(N_NN_C + 255) / 256, 256, 0, stream>>>(receivers, cnt, rank);
        scan1_kernel<<<NB1, 256, 0, stream>>>(cnt, excl, blockTot);
        scan2_kernel<<<1, 128, 0, stream>>>(blockTot, blockOff);
        scan3_kernel<<<(N_NUC_C + 255) / 256, 256, 0, stream>>>(excl, blockOff, offsets);
        scatter_kernel<<<(N_NN_C + 255) / 256, 256, 0, stream>>>(receivers, rank, offsets, edge_order);
        gather_kernel<<<(N_NUC_C + 255) / 256, 256, 0, stream>>>(
            proj, e_embed, senders, edge_order, offsets, ln_scale, ln_bias, W_e, msg);
    } else {
        // --- R1 atomic path ---
        hipMemsetAsync(msg, 0, (size_t)N_NUC_C * MSG_C * 4, stream);
        edge_kernel<<<(N_NN_C + 255) / 256, 256, 0, stream>>>(
            proj, e_embed, senders, receivers, ln_scale, ln_bias, W_e, msg);
    }

    out_kernel<<<2048, 256, 0, stream>>>(msg, norm, W_out, out);
}